// Round 15
// baseline (93.129 us; speedup 1.0000x reference)
//
#include <hip/hip_runtime.h>
#include <hip/hip_bf16.h>

#define TWO_N  8192
#define N_HALF 4096
#define DIMS   256

typedef __bf16 bf16x8 __attribute__((ext_vector_type(8)));
typedef float  f32x4  __attribute__((ext_vector_type(4)));
typedef unsigned short ushort8v __attribute__((ext_vector_type(8)));

// raw v_exp_f32 (args here are bounded |x| <= ~3, no denormal/range handling needed)
__device__ __forceinline__ float fast_exp2(float x) {
#if __has_builtin(__builtin_amdgcn_exp2f)
    return __builtin_amdgcn_exp2f(x);
#else
    float r; asm("v_exp_f32 %0, %1" : "=v"(r) : "v"(x)); return r;
#endif
}

// async global->LDS, 16B per lane: LDS dest = wave-uniform base (HW adds
// lane*16), global src = per-lane pointer (guide §5; m97 pattern).
#define GLOAD_LDS16(g, l)                                                      \
    __builtin_amdgcn_global_load_lds(                                          \
        (const __attribute__((address_space(1))) unsigned int*)(g),            \
        (__attribute__((address_space(3))) unsigned int*)(l), 16, 0, 0)

// ---------------------------------------------------------------------------
// Kernel 1: normalize rows of reps = cat([zjs, zis]), pre-scale by
// sqrt(2*log2(e)) so MFMA dot = (1/TEMP)*log2(e)*sim, and store in MFMA
// fragment-swizzled order: chunk = ((row/16)*8 + kk)*64 + quad*16 + (row%16),
// each chunk = 8 bf16 = elements k in [quad*8 + kk*32, +8) of that row.
// One 32-lane half-wave per row (8 rows / 256-thread block).
// Also zeroes out[0] (stream-ordered before fin1's atomicAdd accumulation).
// ---------------------------------------------------------------------------
__global__ __launch_bounds__(256) void nrm_kernel(const float* __restrict__ zis,
                                                  const float* __restrict__ zjs,
                                                  unsigned short* __restrict__ swz,
                                                  float* __restrict__ out)
{
    if (blockIdx.x == 0 && threadIdx.x == 0) out[0] = 0.f;

    const int tid = threadIdx.x;
    const int l32 = tid & 31;
    const int row = blockIdx.x * 8 + (tid >> 5);
    const int k0  = l32 * 8;

    const float* src = (row < N_HALF) ? (zjs + (size_t)row * DIMS)
                                      : (zis + (size_t)(row - N_HALF) * DIMS);
    const float4 v0 = reinterpret_cast<const float4*>(src + k0)[0];
    const float4 v1 = reinterpret_cast<const float4*>(src + k0 + 4)[0];
    float ss = v0.x * v0.x + v0.y * v0.y + v0.z * v0.z + v0.w * v0.w
             + v1.x * v1.x + v1.y * v1.y + v1.z * v1.z + v1.w * v1.w;
#pragma unroll
    for (int m = 1; m < 32; m <<= 1) ss += __shfl_xor(ss, m, 64);
    // norms ~16 for N(0,1) rows; cosine eps path can never trigger
    const float inv = rsqrtf(ss) * 1.69864360045f;  // * sqrt(2*log2(e))

    const float vals[8] = {v0.x, v0.y, v0.z, v0.w, v1.x, v1.y, v1.z, v1.w};
    ushort8v o;
#pragma unroll
    for (int j = 0; j < 8; ++j) {
        __hip_bfloat16 b = __float2bfloat16(vals[j] * inv);
        o[j] = *reinterpret_cast<unsigned short*>(&b);
    }
    // kk = k0>>5 = l32>>2, quad = l32&3
    const int chunk = ((row >> 4) * 8 + (l32 >> 2)) * 64 + (l32 & 3) * 16 + (row & 15);
    *reinterpret_cast<ushort8v*>(swz + (size_t)chunk * 8) = o;
}

// ---------------------------------------------------------------------------
// Kernel 2 (R8 — best measured, restored verbatim): 512x512 tile, 1 block/CU
// (grid 256), 8 waves, chunked LDS A (4 x 64KB, double-buffered), one
// vmcnt(0)+barrier per 128-col chunk, 16x16x32 MFMA, reg-dbuf a0/a1,
// deferred-epilogue drain (accE/accO).
// Ledger (R8-R14): traffic+rare-barriers = the only wins; occupancy, drain
// shadowing, stagger, setprio, 32x32 shape, 8-chain, cross-block async all
// neutral-to-negative. Effective ~955 TF = the documented plain-HIP
// 2-barrier-structure plateau (m103/m157: 912-948); beyond it requires the
// co-designed 8-phase counted-vmcnt template (m201), a new sync structure.
// ---------------------------------------------------------------------------
__global__ __launch_bounds__(512) void ntx_kernel(const __bf16* __restrict__ swz,
                                                  float* __restrict__ rowsum_part,
                                                  float* __restrict__ pos_part)
{
    __shared__ __bf16 abuf[2][32768];   // 2 x 64 KB (chunk double-buffer)

    const int lane = threadIdx.x & 63;
    const int wave = threadIdx.x >> 6;   // 0..7
    const int l15  = lane & 15;
    const int quad = lane >> 4;

    const int rg   = blockIdx.x & 15;    // 16 row groups of 512
    const int cs   = blockIdx.x >> 4;    // 16 col groups of 512
    const int wr0  = rg * 512 + wave * 64;
    const int p0   = wr0 ^ N_HALF;       // partner-row window (positives)

    // stage chunk c (128 cols = 8 col-16-groups) into abuf[buf]:
    // wave w covers group w (4096 elems = 8 KB) as 8 x 1KB wave-issues.
    auto stage = [&](int buf, int c) {
        const __bf16* gsrc = swz + (size_t)(cs * 32 + c * 8 + wave) * 4096 + lane * 8;
#pragma unroll
        for (int h = 0; h < 8; ++h)
            GLOAD_LDS16(gsrc + h * 512, &abuf[buf][wave * 4096 + h * 512]);
    };

    stage(0, 0);   // chunk 0 in flight while B fragments load

    // Hoist B (row) fragments: 4 groups of 16 rows, 8 K-chunks each (128 VGPR).
    bf16x8 bfrag[4][8];
#pragma unroll
    for (int t = 0; t < 4; ++t) {
        const __bf16* bp = swz + (size_t)((wr0 >> 4) + t) * 4096 + lane * 8;
#pragma unroll
        for (int kk = 0; kk < 8; ++kk)
            bfrag[t][kk] = *reinterpret_cast<const bf16x8*>(bp + kk * 512);
    }

    float sum_exp[4] = {0.f, 0.f, 0.f, 0.f};
    float pos_acc = 0.f;

    // 32-MFMA burst into a named acc set (re-inits the set).
    auto burst = [&](f32x4* acc, const bf16x8* af) {
#pragma unroll
        for (int t = 0; t < 4; ++t) acc[t] = f32x4{0.f, 0.f, 0.f, 0.f};
#pragma unroll
        for (int kk = 0; kk < 8; ++kk) {
#pragma unroll
            for (int t = 0; t < 4; ++t)
                acc[t] = __builtin_amdgcn_mfma_f32_16x16x32_bf16(
                    af[kk], bfrag[t][kk], acc[t], 0, 0, 0);
        }
    };

    // exp2 + row-sum + diag/positive handling for a completed acc set.
    auto drain = [&](const f32x4* acc, int c0) {
        const bool special = (c0 < wr0 + 64 && c0 + 16 > wr0) ||
                             (c0 < p0 + 64 && c0 + 16 > p0);
        if (!special) {
#pragma unroll
            for (int t = 0; t < 4; ++t)
#pragma unroll
                for (int j = 0; j < 4; ++j)
                    sum_exp[t] += fast_exp2(acc[t][j]);
        } else {
#pragma unroll
            for (int t = 0; t < 4; ++t) {
                const int r = wr0 + t * 16 + l15;
#pragma unroll
                for (int j = 0; j < 4; ++j) {
                    const int col = c0 + quad * 4 + j;
                    const float e = fast_exp2(acc[t][j]);
                    sum_exp[t] += (col == r) ? 0.f : e;               // self-diag mask
                    if (col == (r ^ N_HALF)) pos_acc += acc[t][j];    // positive
                }
            }
        }
    };

    asm volatile("s_waitcnt vmcnt(0)" ::: "memory");
    __syncthreads();   // chunk 0 resident

    f32x4 accE[4], accO[4];
    int pc0 = -1;      // pending accO drain column base (-1 = none)

    int cur = 0;
    for (int c = 0; c < 4; ++c) {
        if (c < 3) stage(cur ^ 1, c + 1);   // prefetch next chunk

        const int cc_base = cs * 512 + c * 128;

        bf16x8 a0[8], a1[8];
#pragma unroll
        for (int kk = 0; kk < 8; ++kk)
            a0[kk] = *reinterpret_cast<const bf16x8*>(&abuf[cur][kk * 512 + lane * 8]);

        for (int it = 0; it < 8; it += 2) {
#pragma unroll
            for (int kk = 0; kk < 8; ++kk)
                a1[kk] = *reinterpret_cast<const bf16x8*>(
                    &abuf[cur][(it + 1) * 4096 + kk * 512 + lane * 8]);

            burst(accE, a0);                       // sub-it `it` in flight
            if (pc0 >= 0) drain(accO, pc0);        // prev odd sub-it, shadowed

            if (it + 2 < 8) {
#pragma unroll
                for (int kk = 0; kk < 8; ++kk)
                    a0[kk] = *reinterpret_cast<const bf16x8*>(
                        &abuf[cur][(it + 2) * 4096 + kk * 512 + lane * 8]);
            }

            burst(accO, a1);                       // sub-it `it+1` in flight
            drain(accE, cc_base + it * 16);        // this even sub-it, shadowed
            pc0 = cc_base + (it + 1) * 16;
        }

        // next chunk's stage was issued a full chunk ago -> drain is ~free.
        asm volatile("s_waitcnt vmcnt(0)" ::: "memory");
        __syncthreads();
        cur ^= 1;
    }
    drain(accO, pc0);   // final pending sub-it

    // Per-row partial: reduce over the 4 quads (col groups), one store per row.
#pragma unroll
    for (int t = 0; t < 4; ++t) {
        float s = sum_exp[t];
        s += __shfl_xor(s, 16, 64);
        s += __shfl_xor(s, 32, 64);
        if (lane < 16)
            rowsum_part[(size_t)cs * TWO_N + wr0 + t * 16 + lane] = s;
    }

    // Positive partial: every wave writes its slot (0 if no partner overlap).
#pragma unroll
    for (int m = 1; m < 64; m <<= 1) pos_acc += __shfl_xor(pos_acc, m, 64);
    if (lane == 0) pos_part[blockIdx.x * 8 + wave] = pos_acc;
}

// ---------------------------------------------------------------------------
// Kernel 3 (fin2 fused away): per-row ln(sum of 16 partials) minus ln2 *
// positive partials, block-reduced, then one atomicAdd of s/TWO_N per block
// onto out[0] (zeroed by nrm, stream-ordered). 8-way f32 add reassociation
// error ~1e-5 relative -- far inside tolerance (bf16 inputs already pass).
// ---------------------------------------------------------------------------
__global__ __launch_bounds__(1024) void fin1_kernel(const float* __restrict__ rowsum_part,
                                                    const float* __restrict__ pos_part,
                                                    float* __restrict__ out)
{
    __shared__ float red[16];
    const int t = threadIdx.x;
    const int r = blockIdx.x * 1024 + t;
    float acc = 0.f;
#pragma unroll
    for (int cs = 0; cs < 16; ++cs)
        acc += rowsum_part[(size_t)cs * TWO_N + r];
    float v = logf(acc);
    if (r < 2048)
        v -= 0.69314718055994531f * pos_part[r];
#pragma unroll
    for (int m = 1; m < 64; m <<= 1) v += __shfl_xor(v, m, 64);
    if ((t & 63) == 0) red[t >> 6] = v;
    __syncthreads();
    if (t == 0) {
        float s = 0.f;
#pragma unroll
        for (int w = 0; w < 16; ++w) s += red[w];
        atomicAdd(out, s / (float)TWO_N);
    }
}

// ---------------------------------------------------------------------------
extern "C" void kernel_launch(void* const* d_in, const int* in_sizes, int n_in,
                              void* d_out, int out_size, void* d_ws, size_t ws_size,
                              hipStream_t stream)
{
    const float* zis = (const float*)d_in[0];
    const float* zjs = (const float*)d_in[1];

    // ws: [0,4MB) swizzled bf16; then rowsum partials [16][8192] f32 (512KB);
    //     then pos partials [2048].
    unsigned short* swz = (unsigned short*)d_ws;
    float* rowsum_part  = (float*)((char*)d_ws + (size_t)TWO_N * DIMS * sizeof(unsigned short));
    float* pos_part     = rowsum_part + (size_t)16 * TWO_N;

    nrm_kernel<<<TWO_N / 8, 256, 0, stream>>>(zis, zjs, swz, (float*)d_out);
    ntx_kernel<<<256, 512, 0, stream>>>((const __bf16*)swz, rowsum_part, pos_part);
    fin1_kernel<<<8, 1024, 0, stream>>>(rowsum_part, pos_part, (float*)d_out);
}

// Round 16
// 90.254 us; speedup vs baseline: 1.0319x; 1.0319x over previous
//
#include <hip/hip_runtime.h>
#include <hip/hip_bf16.h>

#define TWO_N  8192
#define N_HALF 4096
#define DIMS   256

typedef __bf16 bf16x8 __attribute__((ext_vector_type(8)));
typedef float  f32x4  __attribute__((ext_vector_type(4)));
typedef unsigned short ushort8v __attribute__((ext_vector_type(8)));

// raw v_exp_f32 (args here are bounded |x| <= ~3, no denormal/range handling needed)
__device__ __forceinline__ float fast_exp2(float x) {
#if __has_builtin(__builtin_amdgcn_exp2f)
    return __builtin_amdgcn_exp2f(x);
#else
    float r; asm("v_exp_f32 %0, %1" : "=v"(r) : "v"(x)); return r;
#endif
}

// async global->LDS, 16B per lane: LDS dest = wave-uniform base (HW adds
// lane*16), global src = per-lane pointer (guide §5; m97 pattern).
#define GLOAD_LDS16(g, l)                                                      \
    __builtin_amdgcn_global_load_lds(                                          \
        (const __attribute__((address_space(1))) unsigned int*)(g),            \
        (__attribute__((address_space(3))) unsigned int*)(l), 16, 0, 0)

// ---------------------------------------------------------------------------
// Kernel 1: normalize rows of reps = cat([zjs, zis]), pre-scale by
// sqrt(2*log2(e)) so MFMA dot = (1/TEMP)*log2(e)*sim, and store in MFMA
// fragment-swizzled order: chunk = ((row/16)*8 + kk)*64 + quad*16 + (row%16),
// each chunk = 8 bf16 = elements k in [quad*8 + kk*32, +8) of that row.
// One 32-lane half-wave per row (8 rows / 256-thread block).
// Also zeroes out[0] (stream-ordered before fin1's atomicAdd accumulation).
// ---------------------------------------------------------------------------
__global__ __launch_bounds__(256) void nrm_kernel(const float* __restrict__ zis,
                                                  const float* __restrict__ zjs,
                                                  unsigned short* __restrict__ swz,
                                                  float* __restrict__ out)
{
    if (blockIdx.x == 0 && threadIdx.x == 0) out[0] = 0.f;

    const int tid = threadIdx.x;
    const int l32 = tid & 31;
    const int row = blockIdx.x * 8 + (tid >> 5);
    const int k0  = l32 * 8;

    const float* src = (row < N_HALF) ? (zjs + (size_t)row * DIMS)
                                      : (zis + (size_t)(row - N_HALF) * DIMS);
    const float4 v0 = reinterpret_cast<const float4*>(src + k0)[0];
    const float4 v1 = reinterpret_cast<const float4*>(src + k0 + 4)[0];
    float ss = v0.x * v0.x + v0.y * v0.y + v0.z * v0.z + v0.w * v0.w
             + v1.x * v1.x + v1.y * v1.y + v1.z * v1.z + v1.w * v1.w;
#pragma unroll
    for (int m = 1; m < 32; m <<= 1) ss += __shfl_xor(ss, m, 64);
    // norms ~16 for N(0,1) rows; cosine eps path can never trigger
    const float inv = rsqrtf(ss) * 1.69864360045f;  // * sqrt(2*log2(e))

    const float vals[8] = {v0.x, v0.y, v0.z, v0.w, v1.x, v1.y, v1.z, v1.w};
    ushort8v o;
#pragma unroll
    for (int j = 0; j < 8; ++j) {
        __hip_bfloat16 b = __float2bfloat16(vals[j] * inv);
        o[j] = *reinterpret_cast<unsigned short*>(&b);
    }
    // kk = k0>>5 = l32>>2, quad = l32&3
    const int chunk = ((row >> 4) * 8 + (l32 >> 2)) * 64 + (l32 & 3) * 16 + (row & 15);
    *reinterpret_cast<ushort8v*>(swz + (size_t)chunk * 8) = o;
}

// ---------------------------------------------------------------------------
// Kernel 2 (4 waves/SIMD + LDS-A): fused scaled-Gram + exp2 row sums + diag
// mask + positive extraction. 256x512 tile, 512-thr blocks = 8 waves x 32
// rows, grid 512 = 2 blocks/CU -> 16 waves/CU = 4/SIMD (VGPR capped 128 via
// __launch_bounds__(512,4)). A staged in 64-col LDS chunks (2 x 32KB dbuf =
// 64KB/block, 128KB/CU), one vmcnt(0)+barrier per chunk (loads issued a full
// chunk early -> drain free).
// WHY: R8's cycle audit shows MFMA(1242) + LDS(770) + VALU(~340) running
// near-SERIALLY per sub-it (2680 measured) -- with only 2 lockstep
// waves/SIMD there is no issue-level interleave; m114 overlap needs more
// heterogeneous wave phases. R5's 4-wave attempt failed on 500cyc GLOBAL
// latency; here A comes from LDS (~120cyc), coverable by 3 partner waves.
// Per-wave footprint trimmed to fit 128 VGPR: bfrag[2][8]=64, single a[8]=32
// (no reg-dbuf; TLP replaces ILP), acc[2]=8. Math bit-identical per row.
// ---------------------------------------------------------------------------
__global__ __launch_bounds__(512, 4) void ntx_kernel(const __bf16* __restrict__ swz,
                                                     float* __restrict__ rowsum_part,
                                                     float* __restrict__ pos_part)
{
    __shared__ __bf16 abuf[2][16384];   // 2 x 32 KB (64-col chunk dbuf)

    const int lane = threadIdx.x & 63;
    const int wave = threadIdx.x >> 6;   // 0..7
    const int l15  = lane & 15;
    const int quad = lane >> 4;

    const int rg   = blockIdx.x & 31;    // 32 row groups of 256
    const int cs   = blockIdx.x >> 5;    // 16 col groups of 512
    const int wr0  = rg * 256 + wave * 32;
    const int p0   = wr0 ^ N_HALF;       // partner-row window (positives)

    // stage chunk c (64 cols = 4 col-16-groups = 32KB): 4 x 1KB issues/wave.
    auto stage = [&](int buf, int c) {
        const __bf16* gsrc = swz + (size_t)(cs * 32 + c * 4) * 4096
                           + (wave * 4) * 512 + lane * 8;
#pragma unroll
        for (int h = 0; h < 4; ++h)
            GLOAD_LDS16(gsrc + h * 512, &abuf[buf][(wave * 4 + h) * 512]);
    };

    stage(0, 0);   // chunk 0 in flight while B fragments load

    // Hoist B (row) fragments: 2 groups of 16 rows, 8 K-chunks each (64 VGPR).
    bf16x8 bfrag[2][8];
#pragma unroll
    for (int t = 0; t < 2; ++t) {
        const __bf16* bp = swz + (size_t)((wr0 >> 4) + t) * 4096 + lane * 8;
#pragma unroll
        for (int kk = 0; kk < 8; ++kk)
            bfrag[t][kk] = *reinterpret_cast<const bf16x8*>(bp + kk * 512);
    }

    float sum_exp[2] = {0.f, 0.f};
    float pos_acc = 0.f;

    asm volatile("s_waitcnt vmcnt(0)" ::: "memory");
    __syncthreads();   // chunk 0 resident

    int cur = 0;
    for (int c = 0; c < 8; ++c) {
        if (c < 7) stage(cur ^ 1, c + 1);   // prefetch next chunk (lands early)

        const int cc_base = cs * 512 + c * 64;

#pragma unroll
        for (int it = 0; it < 4; ++it) {    // 4 sub-its of 16 cols
            bf16x8 a[8];
#pragma unroll
            for (int kk = 0; kk < 8; ++kk)
                a[kk] = *reinterpret_cast<const bf16x8*>(
                    &abuf[cur][it * 4096 + kk * 512 + lane * 8]);

            f32x4 acc[2] = {{0.f, 0.f, 0.f, 0.f}, {0.f, 0.f, 0.f, 0.f}};
#pragma unroll
            for (int kk = 0; kk < 8; ++kk) {
                acc[0] = __builtin_amdgcn_mfma_f32_16x16x32_bf16(
                    a[kk], bfrag[0][kk], acc[0], 0, 0, 0);
                acc[1] = __builtin_amdgcn_mfma_f32_16x16x32_bf16(
                    a[kk], bfrag[1][kk], acc[1], 0, 0, 0);
            }

            const int c0 = cc_base + it * 16;
            // wave rows = [wr0, wr0+32): special iff c0 overlaps self/partner.
            const bool special = (c0 < wr0 + 32 && c0 + 16 > wr0) ||
                                 (c0 < p0 + 32 && c0 + 16 > p0);
            if (!special) {
#pragma unroll
                for (int t = 0; t < 2; ++t)
#pragma unroll
                    for (int j = 0; j < 4; ++j)
                        sum_exp[t] += fast_exp2(acc[t][j]);
            } else {
#pragma unroll
                for (int t = 0; t < 2; ++t) {
                    const int r = wr0 + t * 16 + l15;
#pragma unroll
                    for (int j = 0; j < 4; ++j) {
                        const int col = c0 + quad * 4 + j;
                        const float e = fast_exp2(acc[t][j]);
                        sum_exp[t] += (col == r) ? 0.f : e;               // self-diag
                        if (col == (r ^ N_HALF)) pos_acc += acc[t][j];    // positive
                    }
                }
            }
        }

        // next chunk's loads were issued a full chunk ago -> drain ~free.
        asm volatile("s_waitcnt vmcnt(0)" ::: "memory");
        __syncthreads();
        cur ^= 1;
    }

    // Per-row partial: reduce over the 4 quads (col groups), one store per row.
#pragma unroll
    for (int t = 0; t < 2; ++t) {
        float s = sum_exp[t];
        s += __shfl_xor(s, 16, 64);
        s += __shfl_xor(s, 32, 64);
        if (lane < 16)
            rowsum_part[(size_t)cs * TWO_N + wr0 + t * 16 + lane] = s;
    }

    // Positive partial: every wave writes its slot (0 if no partner overlap).
#pragma unroll
    for (int m = 1; m < 64; m <<= 1) pos_acc += __shfl_xor(pos_acc, m, 64);
    if (lane == 0) pos_part[blockIdx.x * 8 + wave] = pos_acc;
}

// ---------------------------------------------------------------------------
// Kernel 3: per-row ln(sum of 16 partials) minus ln2 * positive partials
// (4096 pos slots; slot->row mapping irrelevant for the global sum),
// block-reduced, one atomicAdd per block onto out[0] (zeroed by nrm).
// ---------------------------------------------------------------------------
__global__ __launch_bounds__(1024) void fin1_kernel(const float* __restrict__ rowsum_part,
                                                    const float* __restrict__ pos_part,
                                                    float* __restrict__ out)
{
    __shared__ float red[16];
    const int t = threadIdx.x;
    const int r = blockIdx.x * 1024 + t;
    float acc = 0.f;
#pragma unroll
    for (int cs = 0; cs < 16; ++cs)
        acc += rowsum_part[(size_t)cs * TWO_N + r];
    float v = logf(acc);
    if (r < 4096)
        v -= 0.69314718055994531f * pos_part[r];
#pragma unroll
    for (int m = 1; m < 64; m <<= 1) v += __shfl_xor(v, m, 64);
    if ((t & 63) == 0) red[t >> 6] = v;
    __syncthreads();
    if (t == 0) {
        float s = 0.f;
#pragma unroll
        for (int w = 0; w < 16; ++w) s += red[w];
        atomicAdd(out, s / (float)TWO_N);
    }
}

// ---------------------------------------------------------------------------
extern "C" void kernel_launch(void* const* d_in, const int* in_sizes, int n_in,
                              void* d_out, int out_size, void* d_ws, size_t ws_size,
                              hipStream_t stream)
{
    const float* zis = (const float*)d_in[0];
    const float* zjs = (const float*)d_in[1];

    // ws: [0,4MB) swizzled bf16; then rowsum partials [16][8192] f32 (512KB);
    //     then pos partials [4096].
    unsigned short* swz = (unsigned short*)d_ws;
    float* rowsum_part  = (float*)((char*)d_ws + (size_t)TWO_N * DIMS * sizeof(unsigned short));
    float* pos_part     = rowsum_part + (size_t)16 * TWO_N;

    nrm_kernel<<<TWO_N / 8, 256, 0, stream>>>(zis, zjs, swz, (float*)d_out);
    ntx_kernel<<<512, 512, 0, stream>>>((const __bf16*)swz, rowsum_part, pos_part);
    fin1_kernel<<<8, 1024, 0, stream>>>(rowsum_part, pos_part, (float*)d_out);
}

// Round 17
// 87.558 us; speedup vs baseline: 1.0636x; 1.0308x over previous
//
#include <hip/hip_runtime.h>
#include <hip/hip_bf16.h>

#define TWO_N  8192
#define N_HALF 4096
#define DIMS   256

typedef float f32x4 __attribute__((ext_vector_type(4)));

// raw v_exp_f32 (args here are bounded |x| <= ~3, no denormal/range handling needed)
__device__ __forceinline__ float fast_exp2(float x) {
#if __has_builtin(__builtin_amdgcn_exp2f)
    return __builtin_amdgcn_exp2f(x);
#else
    float r; asm("v_exp_f32 %0, %1" : "=v"(r) : "v"(x)); return r;
#endif
}

// async global->LDS, 16B per lane: LDS dest = wave-uniform base (HW adds
// lane*16), global src = per-lane pointer (guide §5; m97 pattern).
#define GLOAD_LDS16(g, l)                                                      \
    __builtin_amdgcn_global_load_lds(                                          \
        (const __attribute__((address_space(1))) unsigned int*)(g),            \
        (__attribute__((address_space(3))) unsigned int*)(l), 16, 0, 0)

// ---------------------------------------------------------------------------
// Kernel 1: normalize rows of reps = cat([zjs, zis]), pre-scale by
// sqrt(2*log2(e)) so the fp8 MFMA dot = (1/TEMP)*log2(e)*sim, quantize to
// OCP fp8 e4m3 (v_cvt_pk_fp8_f32, RNE), and store in 16x16x32-fragment
// order: chunk = (row/16)*8 + kk (kk = K/32 step), slot = quad*16 + row%16,
// 8 fp8 bytes = k in [kk*32 + quad*8, +8). One 32-lane half-wave per row.
// Entries ~N(0,0.106^2): e4m3 rel err ~5% -> logit noise sigma~0.013 ->
// final loss error ~1e-4 absolute (pos-term error partially cancels in
// lse - pos since both use the same quantized Gram).
// Also zeroes out[0] (stream-ordered before fin1's atomicAdd).
// ---------------------------------------------------------------------------
__global__ __launch_bounds__(256) void nrm_kernel(const float* __restrict__ zis,
                                                  const float* __restrict__ zjs,
                                                  unsigned char* __restrict__ swz,
                                                  float* __restrict__ out)
{
    if (blockIdx.x == 0 && threadIdx.x == 0) out[0] = 0.f;

    const int tid = threadIdx.x;
    const int l32 = tid & 31;
    const int row = blockIdx.x * 8 + (tid >> 5);
    const int k0  = l32 * 8;

    const float* src = (row < N_HALF) ? (zjs + (size_t)row * DIMS)
                                      : (zis + (size_t)(row - N_HALF) * DIMS);
    const float4 v0 = reinterpret_cast<const float4*>(src + k0)[0];
    const float4 v1 = reinterpret_cast<const float4*>(src + k0 + 4)[0];
    float ss = v0.x * v0.x + v0.y * v0.y + v0.z * v0.z + v0.w * v0.w
             + v1.x * v1.x + v1.y * v1.y + v1.z * v1.z + v1.w * v1.w;
#pragma unroll
    for (int m = 1; m < 32; m <<= 1) ss += __shfl_xor(ss, m, 64);
    // norms ~16 for N(0,1) rows; cosine eps path can never trigger
    const float inv = rsqrtf(ss) * 1.69864360045f;  // * sqrt(2*log2(e))

    // pack 8 scaled values to 8 fp8 bytes (2 ints)
    int w0 = 0, w1 = 0;
    w0 = __builtin_amdgcn_cvt_pk_fp8_f32(v0.x * inv, v0.y * inv, w0, 0);
    w0 = __builtin_amdgcn_cvt_pk_fp8_f32(v0.z * inv, v0.w * inv, w0, 1);
    w1 = __builtin_amdgcn_cvt_pk_fp8_f32(v1.x * inv, v1.y * inv, w1, 0);
    w1 = __builtin_amdgcn_cvt_pk_fp8_f32(v1.z * inv, v1.w * inv, w1, 1);

    // kk = k0>>5 = l32>>2, quad = l32&3; 8B per (chunk,slot)
    const size_t byte = ((size_t)((row >> 4) * 8 + (l32 >> 2)) * 64
                         + (l32 & 3) * 16 + (row & 15)) * 8;
    int2 o; o.x = w0; o.y = w1;
    *reinterpret_cast<int2*>(swz + byte) = o;
}

// ---------------------------------------------------------------------------
// Kernel 2 (fp8 Gram, reuse-4 + 4 waves/SIMD): fused scaled-Gram
// (mfma_f32_16x16x32_fp8_fp8, runs at bf16 rate) + exp2 row sums + diag
// mask + positive extraction.
// WHY fp8: R16's audit showed the bf16 catch-22 -- reuse-4 (bfrag[4], low
// LDS traffic) needs 128 VGPR of B alone (only 2 waves/SIMD, issue-serial,
// R8=91.9), while 4 waves/SIMD forces reuse-2 (LDS floor 20.5us, R16=90.2).
// fp8 halves fragment bytes: bfrag[4][8] = 64 VGPR -> reuse 4 AND 4
// waves/SIMD under the 128 cap. LDS-read floor ~5us, MFMA floor 16.6us ->
// MFMA-bound with TLP to hide everything.
// Geometry: tile 512 rows x 256 cols, grid 512 (rg 16 x cs 32) = 2 blocks/
// CU, 8 waves x 64 rows, A panel 64KB in 4 x 16KB chunks (2x16KB LDS dbuf),
// one vmcnt(0)+barrier per chunk (stage issued a full chunk early).
// Fragment mapping = verified bf16 16x16x32 layout with 8x1B instead of
// 8x2B per lane (k = (lane>>4)*8 + j); C/D layout dtype-independent
// [m121-128]: D row = wr0 + t*16 + l15 (B-side), col = c0 + quad*4 + j.
// ---------------------------------------------------------------------------
__global__ __launch_bounds__(512, 4) void ntx_kernel(const unsigned char* __restrict__ swz,
                                                     float* __restrict__ rowsum_part,
                                                     float* __restrict__ pos_part)
{
    __shared__ unsigned char abuf[2][16384];   // 2 x 16 KB (64-col chunk dbuf)

    const int lane = threadIdx.x & 63;
    const int wave = threadIdx.x >> 6;   // 0..7
    const int l15  = lane & 15;
    const int quad = lane >> 4;

    const int rg   = blockIdx.x & 15;    // 16 row groups of 512
    const int cs   = blockIdx.x >> 4;    // 32 col groups of 256
    const int wr0  = rg * 512 + wave * 64;
    const int p0   = wr0 ^ N_HALF;       // partner-row window (positives)

    // stage chunk c (64 cols = 4 col-16-groups x 8 kk = 16KB): 2 x 1KB
    // issues per wave (wave w covers bytes [w*2048, w*2048+2048)).
    auto stage = [&](int buf, int c) {
        const unsigned char* gsrc = swz + ((size_t)(cs * 128 + c * 32)) * 512
                                  + wave * 2048 + lane * 16;
        GLOAD_LDS16(gsrc,       &abuf[buf][wave * 2048]);
        GLOAD_LDS16(gsrc + 1024, &abuf[buf][wave * 2048 + 1024]);
    };

    stage(0, 0);   // chunk 0 in flight while B fragments load

    // Hoist B (row) fragments: 4 groups of 16 rows, 8 K-chunks each,
    // 8 fp8 bytes = 1 long long each -> 64 VGPR total.
    long long bfrag[4][8];
#pragma unroll
    for (int t = 0; t < 4; ++t) {
        const unsigned char* bp = swz + (size_t)((wr0 >> 4) + t) * 4096 + lane * 8;
#pragma unroll
        for (int kk = 0; kk < 8; ++kk)
            bfrag[t][kk] = *reinterpret_cast<const long long*>(bp + kk * 512);
    }

    float sum_exp[4] = {0.f, 0.f, 0.f, 0.f};
    float pos_acc = 0.f;

    asm volatile("s_waitcnt vmcnt(0)" ::: "memory");
    __syncthreads();   // chunk 0 resident

    int cur = 0;
    for (int c = 0; c < 4; ++c) {
        if (c < 3) stage(cur ^ 1, c + 1);   // prefetch next chunk (lands early)

        const int cc_base = cs * 256 + c * 64;

#pragma unroll
        for (int it = 0; it < 4; ++it) {    // 4 sub-its of 16 cols
            const unsigned char* ab = &abuf[cur][it * 4096 + lane * 8];

            f32x4 acc[4] = {{0.f, 0.f, 0.f, 0.f}, {0.f, 0.f, 0.f, 0.f},
                            {0.f, 0.f, 0.f, 0.f}, {0.f, 0.f, 0.f, 0.f}};
            // a loaded in two halves of 4 kk (8 VGPR live) to stay under cap
#pragma unroll
            for (int h = 0; h < 2; ++h) {
                long long a[4];
#pragma unroll
                for (int k4 = 0; k4 < 4; ++k4)
                    a[k4] = *reinterpret_cast<const long long*>(ab + (h * 4 + k4) * 512);
#pragma unroll
                for (int k4 = 0; k4 < 4; ++k4) {
#pragma unroll
                    for (int t = 0; t < 4; ++t)
                        acc[t] = __builtin_amdgcn_mfma_f32_16x16x32_fp8_fp8(
                            a[k4], bfrag[t][h * 4 + k4], acc[t], 0, 0, 0);
                }
            }

            const int c0 = cc_base + it * 16;
            const bool special = (c0 < wr0 + 64 && c0 + 16 > wr0) ||
                                 (c0 < p0 + 64 && c0 + 16 > p0);
            if (!special) {
#pragma unroll
                for (int t = 0; t < 4; ++t)
#pragma unroll
                    for (int j = 0; j < 4; ++j)
                        sum_exp[t] += fast_exp2(acc[t][j]);
            } else {
#pragma unroll
                for (int t = 0; t < 4; ++t) {
                    const int r = wr0 + t * 16 + l15;
#pragma unroll
                    for (int j = 0; j < 4; ++j) {
                        const int col = c0 + quad * 4 + j;
                        const float e = fast_exp2(acc[t][j]);
                        sum_exp[t] += (col == r) ? 0.f : e;               // self-diag
                        if (col == (r ^ N_HALF)) pos_acc += acc[t][j];    // positive
                    }
                }
            }
        }

        // next chunk's loads were issued a full chunk ago -> drain ~free.
        asm volatile("s_waitcnt vmcnt(0)" ::: "memory");
        __syncthreads();
        cur ^= 1;
    }

    // Per-row partial: reduce over the 4 quads (col groups), one store per row.
#pragma unroll
    for (int t = 0; t < 4; ++t) {
        float s = sum_exp[t];
        s += __shfl_xor(s, 16, 64);
        s += __shfl_xor(s, 32, 64);
        if (lane < 16)
            rowsum_part[(size_t)cs * TWO_N + wr0 + t * 16 + lane] = s;
    }

    // Positive partial: every wave writes its slot (0 if no partner overlap).
#pragma unroll
    for (int m = 1; m < 64; m <<= 1) pos_acc += __shfl_xor(pos_acc, m, 64);
    if (lane == 0) pos_part[blockIdx.x * 8 + wave] = pos_acc;
}

// ---------------------------------------------------------------------------
// Kernel 3: per-row ln(sum of 32 partials) minus ln2 * positive partials
// (4096 pos slots; slot->row mapping irrelevant for the global sum),
// block-reduced, one atomicAdd per block onto out[0] (zeroed by nrm).
// ---------------------------------------------------------------------------
__global__ __launch_bounds__(1024) void fin1_kernel(const float* __restrict__ rowsum_part,
                                                    const float* __restrict__ pos_part,
                                                    float* __restrict__ out)
{
    __shared__ float red[16];
    const int t = threadIdx.x;
    const int r = blockIdx.x * 1024 + t;
    float acc = 0.f;
#pragma unroll
    for (int cs = 0; cs < 32; ++cs)
        acc += rowsum_part[(size_t)cs * TWO_N + r];
    float v = logf(acc);
    if (r < 4096)
        v -= 0.69314718055994531f * pos_part[r];
#pragma unroll
    for (int m = 1; m < 64; m <<= 1) v += __shfl_xor(v, m, 64);
    if ((t & 63) == 0) red[t >> 6] = v;
    __syncthreads();
    if (t == 0) {
        float s = 0.f;
#pragma unroll
        for (int w = 0; w < 16; ++w) s += red[w];
        atomicAdd(out, s / (float)TWO_N);
    }
}

// ---------------------------------------------------------------------------
extern "C" void kernel_launch(void* const* d_in, const int* in_sizes, int n_in,
                              void* d_out, int out_size, void* d_ws, size_t ws_size,
                              hipStream_t stream)
{
    const float* zis = (const float*)d_in[0];
    const float* zjs = (const float*)d_in[1];

    // ws: [0,2MB) swizzled fp8; then rowsum partials [32][8192] f32 (1MB);
    //     then pos partials [4096].
    unsigned char* swz = (unsigned char*)d_ws;
    float* rowsum_part = (float*)((char*)d_ws + (size_t)TWO_N * DIMS);
    float* pos_part    = rowsum_part + (size_t)32 * TWO_N;

    nrm_kernel<<<TWO_N / 8, 256, 0, stream>>>(zis, zjs, swz, (float*)d_out);
    ntx_kernel<<<512, 512, 0, stream>>>(swz, rowsum_part, pos_part);
    fin1_kernel<<<8, 1024, 0, stream>>>(rowsum_part, pos_part, (float*)d_out);
}